// Round 1
// baseline (1169.578 us; speedup 1.0000x reference)
//
#include <hip/hip_runtime.h>
#include <cstdint>
#include <cstddef>

#define NN      10000
#define NE      320000
#define FINF    2
#define HIDN    64
#define OUTN    16
#define BBATCH  4
#define TSTEPS  12
#define NBROWS  (NN * BBATCH)          // 40000 (n-major, row = n*B + b)
#define XTN     (TSTEPS * NN * BBATCH * FINF)   // 960000

// ---------------- graph preprocessing ----------------

__global__ void hist_kernel(const int* __restrict__ dst, int* __restrict__ cnt) {
    int e = blockIdx.x * 256 + threadIdx.x;
    if (e < NE) atomicAdd(&cnt[dst[e]], 1);
}

// single-block exclusive scan over per-node counts -> rowstart[N+1], cursor copy
__global__ void scan_kernel(const int* __restrict__ cnt, int* __restrict__ rowstart,
                            int* __restrict__ cursor) {
    __shared__ int part[1024];
    const int tid = threadIdx.x;
    const int CH = (NN + 1023) / 1024;   // 10
    int base = tid * CH;
    int s = 0;
    for (int i = 0; i < CH; ++i) {
        int idx = base + i;
        if (idx < NN) s += cnt[idx];
    }
    part[tid] = s;
    __syncthreads();
    for (int off = 1; off < 1024; off *= 2) {
        int v = (tid >= off) ? part[tid - off] : 0;
        __syncthreads();
        part[tid] += v;
        __syncthreads();
    }
    int run = (tid == 0) ? 0 : part[tid - 1];
    for (int i = 0; i < CH; ++i) {
        int idx = base + i;
        if (idx < NN) {
            rowstart[idx] = run;
            cursor[idx]   = run;
            run += cnt[idx];
        }
    }
    if (tid == 1023) rowstart[NN] = part[1023];
}

__global__ void scatter_kernel(const int* __restrict__ src, const int* __restrict__ dst,
                               const float* __restrict__ w, int* __restrict__ cursor,
                               int* __restrict__ csr_src, float* __restrict__ csr_w) {
    int e = blockIdx.x * 256 + threadIdx.x;
    if (e >= NE) return;
    int d = dst[e];
    int p = atomicAdd(&cursor[d], 1);
    csr_src[p] = src[e];
    csr_w[p]   = w[e];
}

// deg[n] = 1 (self loop) + sum of incoming weights; dinv = rsqrt(deg)
__global__ void deg_kernel(const int* __restrict__ rowstart, const float* __restrict__ csr_w,
                           float* __restrict__ dinv) {
    int n = blockIdx.x * 256 + threadIdx.x;
    if (n >= NN) return;
    float s = 1.0f;
    int a = rowstart[n], b = rowstart[n + 1];
    for (int i = a; i < b; ++i) s += csr_w[i];
    dinv[n] = (s > 0.f) ? rsqrtf(s) : 0.f;
}

// x[B][N][FIN][T] -> xT[t][n][b][f]  (row (t,n) = 8 contiguous floats)
__global__ void transpose_kernel(const float* __restrict__ x, float* __restrict__ xT) {
    int idx = blockIdx.x * 256 + threadIdx.x;
    if (idx >= XTN) return;
    int f = idx & 1;
    int b = (idx >> 1) & 3;
    int v = idx >> 3;            // t*NN + n
    int n = v % NN;
    int t = v / NN;
    xT[idx] = x[((size_t)(b * NN + n) * FINF + f) * TSTEPS + t];
}

// agg[t][n][:] = dinv[n]^2 * xT[t][n][:] + sum_in_edges dinv[n]*w*dinv[src] * xT[t][src][:]
__global__ void aggregate_kernel(const float* __restrict__ xT, const int* __restrict__ rowstart,
                                 const int* __restrict__ csr_src, const float* __restrict__ csr_w,
                                 const float* __restrict__ dinv, float* __restrict__ agg) {
    int idx = blockIdx.x * 256 + threadIdx.x;      // over T*N
    if (idx >= TSTEPS * NN) return;
    int t = idx / NN;
    int n = idx - t * NN;
    float dn = dinv[n];
    float c0 = dn * dn;
    const float4* xr = (const float4*)(xT + (size_t)idx * 8);
    float4 lo = xr[0], hi = xr[1];
    float al[8];
    al[0] = c0 * lo.x; al[1] = c0 * lo.y; al[2] = c0 * lo.z; al[3] = c0 * lo.w;
    al[4] = c0 * hi.x; al[5] = c0 * hi.y; al[6] = c0 * hi.z; al[7] = c0 * hi.w;
    int s = rowstart[n], e = rowstart[n + 1];
    for (int i = s; i < e; ++i) {
        int sn = csr_src[i];
        float c = dn * csr_w[i] * dinv[sn];
        const float4* xs = (const float4*)(xT + ((size_t)t * NN + sn) * 8);
        float4 slo = xs[0], shi = xs[1];
        al[0] = fmaf(c, slo.x, al[0]); al[1] = fmaf(c, slo.y, al[1]);
        al[2] = fmaf(c, slo.z, al[2]); al[3] = fmaf(c, slo.w, al[3]);
        al[4] = fmaf(c, shi.x, al[4]); al[5] = fmaf(c, shi.y, al[5]);
        al[6] = fmaf(c, shi.z, al[6]); al[7] = fmaf(c, shi.w, al[7]);
    }
    float4* ap = (float4*)(agg + (size_t)idx * 8);
    ap[0] = make_float4(al[0], al[1], al[2], al[3]);
    ap[1] = make_float4(al[4], al[5], al[6], al[7]);
}

// ---------------- parameter folding ----------------
// PP layout (floats):
//   [0)      Lzb[64][64]   = Lz_w rows 64..127
//   [4096)   Lrb[64][64]
//   [8192)   Lhb[64][64]
//   [12288)  W2[3][2][64]  = Wg @ Lg_top
//   [12672)  b2[3][64]     = bg @ Lg_top + Lg_b
//   [12864)  lin_w[64][16]
//   [13888)  lin_b[16]     (total 13904)
__global__ void prep_params(const float* __restrict__ Wz, const float* __restrict__ bz,
                            const float* __restrict__ Wr, const float* __restrict__ br,
                            const float* __restrict__ Wh, const float* __restrict__ bh,
                            const float* __restrict__ Lz, const float* __restrict__ Lz_b,
                            const float* __restrict__ Lr, const float* __restrict__ Lr_b,
                            const float* __restrict__ Lh, const float* __restrict__ Lh_b,
                            const float* __restrict__ linw, const float* __restrict__ linb,
                            float* __restrict__ PP) {
    int i = blockIdx.x * 256 + threadIdx.x;
    const float* Lg[3]   = {Lz, Lr, Lh};
    const float* Lbias[3]= {Lz_b, Lr_b, Lh_b};
    const float* Wg[3]   = {Wz, Wr, Wh};
    const float* bg[3]   = {bz, br, bh};
    if (i < 12288) {
        int g = i >> 12, rr = (i >> 6) & 63, j = i & 63;
        PP[i] = Lg[g][(64 + rr) * 64 + j];
    } else if (i < 12672) {
        int i2 = i - 12288;
        int g = i2 >> 7, f = (i2 >> 6) & 1, j = i2 & 63;
        float s = 0.f;
        for (int k = 0; k < 64; ++k) s = fmaf(Wg[g][f * 64 + k], Lg[g][k * 64 + j], s);
        PP[i] = s;
    } else if (i < 12864) {
        int i3 = i - 12672;
        int g = i3 >> 6, j = i3 & 63;
        float s = Lbias[g][j];
        for (int k = 0; k < 64; ++k) s = fmaf(bg[g][k], Lg[g][k * 64 + j], s);
        PP[i] = s;
    } else if (i < 13888) {
        PP[i] = linw[i - 12864];
    } else if (i < 13904) {
        PP[i] = linb[i - 13888];
    }
}

// ---------------- recurrent GRU (row-local across all 12 steps) ----------------
// block = 256 threads = 4 waves; 64 rows/block; wave q handles j-chunk [16q,16q+16)
// (weight addresses are wave-uniform -> one 16B L1 request per load).
// H and H*R in LDS with stride 65 (2-way bank aliasing = free).
__global__ __launch_bounds__(256, 2)
void recurrent_kernel(const float* __restrict__ agg, const float* __restrict__ PP,
                      float* __restrict__ out) {
    __shared__ float Hs[64 * 65];
    __shared__ float HRs[64 * 65];
    const int tid = threadIdx.x;
    const int q = tid >> 6;          // wave id = j-chunk
    const int r = tid & 63;          // row within block
    const int row = blockIdx.x * 64 + r;
    const int n = row >> 2;
    const int b = row & 3;
    const int j0 = q * 16;

    for (int i = tid; i < 64 * 65; i += 256) { Hs[i] = 0.f; HRs[i] = 0.f; }
    __syncthreads();

    const float* __restrict__ Lzb  = PP;
    const float* __restrict__ Lrb  = PP + 4096;
    const float* __restrict__ Lhb  = PP + 8192;
    const float* __restrict__ W2   = PP + 12288;
    const float* __restrict__ b2   = PP + 12672;
    const float* __restrict__ lin  = PP + 12864;
    const float* __restrict__ linb = PP + 13888;

    for (int t = 0; t < TSTEPS; ++t) {
        const float* ag = agg + (size_t)(t * NBROWS + row) * 2;
        const float a0 = ag[0], a1 = ag[1];

        // ---- phase 1: Z, R pre-activations ----
        float accZ[16], accR[16];
        #pragma unroll
        for (int jj = 0; jj < 16; ++jj) {
            int j = j0 + jj;
            accZ[jj] = fmaf(a1, W2[64 + j],  fmaf(a0, W2[j],       b2[j]));
            accR[jj] = fmaf(a1, W2[192 + j], fmaf(a0, W2[128 + j], b2[64 + j]));
        }
        #pragma unroll 4
        for (int k = 0; k < 64; ++k) {
            const float h = Hs[r * 65 + k];
            const float4* wz = (const float4*)(Lzb + k * 64 + j0);
            const float4* wr = (const float4*)(Lrb + k * 64 + j0);
            #pragma unroll
            for (int v = 0; v < 4; ++v) {
                float4 z4 = wz[v];
                float4 r4 = wr[v];
                accZ[v*4+0] = fmaf(h, z4.x, accZ[v*4+0]);
                accZ[v*4+1] = fmaf(h, z4.y, accZ[v*4+1]);
                accZ[v*4+2] = fmaf(h, z4.z, accZ[v*4+2]);
                accZ[v*4+3] = fmaf(h, z4.w, accZ[v*4+3]);
                accR[v*4+0] = fmaf(h, r4.x, accR[v*4+0]);
                accR[v*4+1] = fmaf(h, r4.y, accR[v*4+1]);
                accR[v*4+2] = fmaf(h, r4.z, accR[v*4+2]);
                accR[v*4+3] = fmaf(h, r4.w, accR[v*4+3]);
            }
        }
        float Z[16], Rg[16];
        #pragma unroll
        for (int jj = 0; jj < 16; ++jj) {
            Z[jj]  = 1.f / (1.f + __expf(-accZ[jj]));
            Rg[jj] = 1.f / (1.f + __expf(-accR[jj]));
        }
        #pragma unroll
        for (int jj = 0; jj < 16; ++jj)
            HRs[r * 65 + j0 + jj] = Hs[r * 65 + j0 + jj] * Rg[jj];
        __syncthreads();   // HR complete; phase-1 Hs reads complete

        // ---- phase 3: H_tilde ----
        float accH[16];
        #pragma unroll
        for (int jj = 0; jj < 16; ++jj) {
            int j = j0 + jj;
            accH[jj] = fmaf(a1, W2[320 + j], fmaf(a0, W2[256 + j], b2[128 + j]));
        }
        #pragma unroll 4
        for (int k = 0; k < 64; ++k) {
            const float hr = HRs[r * 65 + k];
            const float4* wh = (const float4*)(Lhb + k * 64 + j0);
            #pragma unroll
            for (int v = 0; v < 4; ++v) {
                float4 h4 = wh[v];
                accH[v*4+0] = fmaf(hr, h4.x, accH[v*4+0]);
                accH[v*4+1] = fmaf(hr, h4.y, accH[v*4+1]);
                accH[v*4+2] = fmaf(hr, h4.z, accH[v*4+2]);
                accH[v*4+3] = fmaf(hr, h4.w, accH[v*4+3]);
            }
        }

        // ---- phase 4: gate combine ----
        float Hn[16];
        #pragma unroll
        for (int jj = 0; jj < 16; ++jj) {
            float ht = tanhf(accH[jj]);
            float h  = Hs[r * 65 + j0 + jj];
            Hn[jj] = Z[jj] * h + (1.f - Z[jj]) * ht;
        }
        __syncthreads();   // all reads of old H complete
        #pragma unroll
        for (int jj = 0; jj < 16; ++jj)
            Hs[r * 65 + j0 + jj] = Hn[jj];
        __syncthreads();   // new H visible

        // ---- phase 6: output projection: relu(H) @ lin_w + lin_b ----
        float o0 = linb[q*4+0], o1 = linb[q*4+1], o2 = linb[q*4+2], o3 = linb[q*4+3];
        #pragma unroll 8
        for (int j = 0; j < 64; ++j) {
            float h = fmaxf(Hs[r * 65 + j], 0.f);
            float4 lw = *(const float4*)(lin + j * 16 + q * 4);
            o0 = fmaf(h, lw.x, o0);
            o1 = fmaf(h, lw.y, o1);
            o2 = fmaf(h, lw.z, o2);
            o3 = fmaf(h, lw.w, o3);
        }
        float4* op = (float4*)(out + ((size_t)(b * TSTEPS + t) * NN + n) * 16 + q * 4);
        *op = make_float4(o0, o1, o2, o3);
    }
}

// ---------------- launch ----------------

extern "C" void kernel_launch(void* const* d_in, const int* in_sizes, int n_in,
                              void* d_out, int out_size, void* d_ws, size_t ws_size,
                              hipStream_t stream) {
    const float* x   = (const float*)d_in[0];
    const int*   ei  = (const int*)d_in[1];
    const float* ew  = (const float*)d_in[2];
    const float* Wz  = (const float*)d_in[3];
    const float* bz  = (const float*)d_in[4];
    const float* Wr  = (const float*)d_in[5];
    const float* br  = (const float*)d_in[6];
    const float* Wh  = (const float*)d_in[7];
    const float* bh  = (const float*)d_in[8];
    const float* Lz  = (const float*)d_in[9];
    const float* Lz_b= (const float*)d_in[10];
    const float* Lr  = (const float*)d_in[11];
    const float* Lr_b= (const float*)d_in[12];
    const float* Lh  = (const float*)d_in[13];
    const float* Lh_b= (const float*)d_in[14];
    const float* lw  = (const float*)d_in[15];
    const float* lb  = (const float*)d_in[16];
    float* out = (float*)d_out;

    char* ws = (char*)d_ws;
    size_t off = 0;
    auto alloc = [&](size_t bytes) -> char* {
        char* p = ws + off;
        off += (bytes + 15) & ~(size_t)15;
        return p;
    };
    float* xT       = (float*)alloc((size_t)XTN * 4);
    float* agg      = (float*)alloc((size_t)XTN * 4);
    float* PP       = (float*)alloc(13904 * 4);
    float* csr_w    = (float*)alloc((size_t)NE * 4);
    int*   csr_src  = (int*)  alloc((size_t)NE * 4);
    int*   rowstart = (int*)  alloc((NN + 1) * 4);
    int*   cursor   = (int*)  alloc(NN * 4);
    int*   cnt      = (int*)  alloc(NN * 4);
    float* dinv     = (float*)alloc(NN * 4);

    const int* srcp = ei;
    const int* dstp = ei + NE;

    hipMemsetAsync(cnt, 0, NN * sizeof(int), stream);
    hist_kernel<<<(NE + 255) / 256, 256, 0, stream>>>(dstp, cnt);
    scan_kernel<<<1, 1024, 0, stream>>>(cnt, rowstart, cursor);
    scatter_kernel<<<(NE + 255) / 256, 256, 0, stream>>>(srcp, dstp, ew, cursor, csr_src, csr_w);
    deg_kernel<<<(NN + 255) / 256, 256, 0, stream>>>(rowstart, csr_w, dinv);
    transpose_kernel<<<(XTN + 255) / 256, 256, 0, stream>>>(x, xT);
    prep_params<<<(13904 + 255) / 256, 256, 0, stream>>>(Wz, bz, Wr, br, Wh, bh,
                                                          Lz, Lz_b, Lr, Lr_b, Lh, Lh_b,
                                                          lw, lb, PP);
    aggregate_kernel<<<(TSTEPS * NN + 255) / 256, 256, 0, stream>>>(xT, rowstart, csr_src,
                                                                    csr_w, dinv, agg);
    recurrent_kernel<<<NBROWS / 64, 256, 0, stream>>>(agg, PP, out);
}